// Round 11
// baseline (177.001 us; speedup 1.0000x reference)
//
#include <hip/hip_runtime.h>
#include <stdint.h>

typedef __bf16 bf16x8 __attribute__((ext_vector_type(8)));
typedef __bf16 bf16x4 __attribute__((ext_vector_type(4)));
typedef float  f32x16 __attribute__((ext_vector_type(16)));

constexpr int kB = 16;
constexpr int kN = 1024;
constexpr float kLog2e = 1.44269504088896340736f;

struct bfhl { __bf16 h, l; };
__device__ __forceinline__ bfhl hilo(float v) {
    bfhl r;
    r.h = (__bf16)v;
    r.l = (__bf16)(v - (float)r.h);
    return r;
}

// m-offset ordering of P fragments: P0[j] holds row (j<4 ? j+4h : j+4+4h),
// P1 the same +16. V fragments are written in the identical order.
__device__ __forceinline__ int moff(int f, int h, int j) {
    return 16 * f + ((j < 4) ? (4 * h + j) : (4 * h + j + 4));
}

// apply main loop: ILP-2 S-chains + next-iter prefetch (round-10 proven body)
__device__ __forceinline__ void apply_loop(
    const __bf16* __restrict__ esfB, const __bf16* __restrict__ vtfB,
    int w, int l, bf16x8 bhi, bf16x8 blo, f32x16& acc, float& Lp)
{
#define LOADK(kt, ahi, alo, V0, V1) \
    ahi = *(const bf16x8*)(esfB + ((size_t)(kt) * 2) * 512 + l * 8);     \
    alo = *(const bf16x8*)(esfB + ((size_t)(kt) * 2 + 1) * 512 + l * 8); \
    V0  = *(const bf16x8*)(vtfB + ((size_t)(kt) * 2) * 512 + l * 8);     \
    V1  = *(const bf16x8*)(vtfB + ((size_t)(kt) * 2 + 1) * 512 + l * 8);

    const int ktb = w * 8;
    bf16x8 cahiA, caloA, cV0A, cV1A, cahiB, caloB, cV0B, cV1B;
    LOADK(ktb + 0, cahiA, caloA, cV0A, cV1A);
    LOADK(ktb + 1, cahiB, caloB, cV0B, cV1B);

    #pragma unroll
    for (int it = 0; it < 4; ++it) {
        bf16x8 nahiA, naloA, nV0A, nV1A, nahiB, naloB, nV0B, nV1B;
        if (it < 3) {
            LOADK(ktb + it * 2 + 2, nahiA, naloA, nV0A, nV1A);
            LOADK(ktb + it * 2 + 3, nahiB, naloB, nV0B, nV1B);
        }
        f32x16 S0 = {}, S1 = {};
        S0 = __builtin_amdgcn_mfma_f32_32x32x16_bf16(cahiA, bhi, S0, 0, 0, 0);
        S1 = __builtin_amdgcn_mfma_f32_32x32x16_bf16(cahiB, bhi, S1, 0, 0, 0);
        S0 = __builtin_amdgcn_mfma_f32_32x32x16_bf16(cahiA, blo, S0, 0, 0, 0);
        S1 = __builtin_amdgcn_mfma_f32_32x32x16_bf16(cahiB, blo, S1, 0, 0, 0);
        S0 = __builtin_amdgcn_mfma_f32_32x32x16_bf16(caloA, bhi, S0, 0, 0, 0);
        S1 = __builtin_amdgcn_mfma_f32_32x32x16_bf16(caloB, bhi, S1, 0, 0, 0);

        float p0[16], p1[16];
        #pragma unroll
        for (int r = 0; r < 16; ++r) {
            p0[r] = exp2f(fmaxf(S0[r], 0.f));  Lp += p0[r];
            p1[r] = exp2f(fmaxf(S1[r], 0.f));  Lp += p1[r];
        }
        bf16x8 P00, P01, P10, P11;
        #pragma unroll
        for (int j = 0; j < 8; ++j) {
            P00[j] = (__bf16)p0[j]; P01[j] = (__bf16)p0[8 + j];
            P10[j] = (__bf16)p1[j]; P11[j] = (__bf16)p1[8 + j];
        }
        acc = __builtin_amdgcn_mfma_f32_32x32x16_bf16(cV0A, P00, acc, 0, 0, 0);
        acc = __builtin_amdgcn_mfma_f32_32x32x16_bf16(cV1A, P01, acc, 0, 0, 0);
        acc = __builtin_amdgcn_mfma_f32_32x32x16_bf16(cV0B, P10, acc, 0, 0, 0);
        acc = __builtin_amdgcn_mfma_f32_32x32x16_bf16(cV1B, P11, acc, 0, 0, 0);

        cahiA = nahiA; caloA = naloA; cV0A = nV0A; cV1A = nV1A;
        cahiB = nahiB; caloB = naloB; cV0B = nV0B; cV1B = nV1B;
    }
#undef LOADK
}

// ---------------------------------------------------------------------------
// Single kernel, grid 512 (= 256 CUs x 2 blocks, all co-resident), 256 thr.
// Phase 0: per-block slice conversion (emb->esf, x->vtf1, own Q-frags in regs,
//          W->wq on blocks 0..47, stock->LDS) ; flag-barrier per batch.
// Phase 1: apply1 (V=vtf1) -> y1 in LDS (yb) + vtf2 slice ; flag-barrier.
// Phase 2: apply2 (V=vtf2) + fused final GEMM -> out.
// Barriers: per-block release-STORE to own flag (no RMW contention);
// 32 poller lanes spin on the batch's 32 flags; acquire fence after.
// ---------------------------------------------------------------------------
__global__ __launch_bounds__(256, 2) void dygcn_one(
    const float* __restrict__ emb, const float* __restrict__ x,
    const float* __restrict__ Wp, const float* __restrict__ stock,
    const float* __restrict__ bias,
    __bf16* __restrict__ esf, __bf16* __restrict__ vtf1,
    __bf16* __restrict__ vtf2, __bf16* __restrict__ wq,
    uint32_t* flags,    // [0..511] phase0, [512..1023] phase1, [1024..1071] W
    float* __restrict__ out)
{
    __shared__ alignas(16) char smem[28672];
    float*  ps  = (float*)smem;             // 4224 f32 (phase0: x staging)
    float*  Ls  = (float*)(smem + 16896);   // 128 f32
    float*  yb  = (float*)(smem + 17408);   // 1152 f32 (ph0: E staging; ph1: y1)
    __bf16* xg2 = (__bf16*)(smem + 22016);  // [2][32][36] bf16
    float*  s_s = (float*)(smem + 26624);   // 32*16 f32 (stock)

    const int tid = threadIdx.x;
    const int w = tid >> 6, l = tid & 63;
    const int q = l & 31, h = l >> 5;
    const int bs = ((blockIdx.x & 7) << 6) | (blockIdx.x >> 3);   // XCD swizzle
    const int b = bs >> 5, nt = bs & 31, q0 = nt << 5;
    const int gnt = b * 32 + nt;

    const __bf16* esfB = esf + (size_t)b * 32768;

    // ================= phase 0: convert own slices =================
    float* xls = ps;   // [32][36]
    float* Els = yb;   // [32][16]
    {   // x tile -> LDS
        int row = tid >> 3, q8 = tid & 7;
        float4 v = *(const float4*)(x + (size_t)(b * kN + q0 + row) * 32 + q8 * 4);
        *(float4*)(&xls[row * 36 + q8 * 4]) = v;
    }
    if (tid < 128) {   // E tile -> LDS
        int row = tid >> 2, seg = tid & 3;
        float4 v = *(const float4*)(emb + (size_t)(b * kN + q0 + row) * 16 + seg * 4);
        *(float4*)(&Els[row * 16 + seg * 4]) = v;
    }
    {   // stock -> s_s (persists to phase 2)
        int r = tid >> 3, e2 = (tid & 7) * 2;
        *(float2*)(s_s + r * 16 + e2) =
            *(const float2*)(stock + (size_t)(b * kN + q0 + r) * 16 + e2);
    }
    if (blockIdx.x < 48 && tid < 128) {   // W -> wq (hi plane)
        int idx = blockIdx.x * 128 + tid;   // (e, ks, o, hh)
        int e = idx / 384, rem = idx - e * 384;
        int ks = rem / 64, r2 = rem - ks * 64;
        int o = r2 >> 1, hh = r2 & 1;
        int ki0 = ks * 16 + hh * 8;
        bf16x8 hi;
        #pragma unroll
        for (int j = 0; j < 8; ++j)
            hi[j] = (__bf16)Wp[(size_t)e * 3072 + (size_t)(ki0 + j) * 32 + o];
        *(bf16x8*)(wq + (size_t)(e * 6 + ks) * 512 + o * 16 + hh * 8) = hi;
    }
    __syncthreads();
    if (tid < 64) {   // esf slice (own kt = nt): hi + lo planes
        bf16x8 hi, lo;
        #pragma unroll
        for (int j = 0; j < 8; ++j) {
            bfhl t = hilo(Els[(tid & 31) * 16 + (tid >> 5) * 8 + j]);
            hi[j] = t.h; lo[j] = t.l;
        }
        *(bf16x8*)(esf + ((size_t)gnt * 2 + 0) * 512 + tid * 8) = hi;
        *(bf16x8*)(esf + ((size_t)gnt * 2 + 1) * 512 + tid * 8) = lo;
    }
    if (tid < 128) {   // vtf1 slice (own mt = nt), hi plane
        int fr = tid >> 6, l2 = tid & 63;
        int d = l2 & 31, h2 = l2 >> 5;
        bf16x8 ov;
        #pragma unroll
        for (int j = 0; j < 8; ++j)
            ov[j] = (__bf16)xls[moff(fr, h2, j) * 36 + d];
        *(bf16x8*)(vtf1 + ((size_t)gnt * 2 + fr) * 512 + l2 * 8) = ov;
    }
    // own Q-side fragments (log2e-scaled) -> registers
    bf16x8 bhi, blo;
    #pragma unroll
    for (int j = 0; j < 8; ++j) {
        bfhl t = hilo(Els[q * 16 + 8 * h + j] * kLog2e);
        bhi[j] = t.h; blo[j] = t.l;
    }

    // ---- barrier 0: publish esf + vtf1 (+ wq) ----
    __threadfence();
    __syncthreads();
    if (tid == 0) {
        __hip_atomic_store(&flags[b * 32 + nt], 1u, __ATOMIC_RELEASE, __HIP_MEMORY_SCOPE_AGENT);
        if (blockIdx.x < 48)
            __hip_atomic_store(&flags[1024 + blockIdx.x], 1u, __ATOMIC_RELEASE, __HIP_MEMORY_SCOPE_AGENT);
    }
    if (tid < 32)
        while (!__hip_atomic_load(&flags[b * 32 + tid], __ATOMIC_RELAXED, __HIP_MEMORY_SCOPE_AGENT))
            __builtin_amdgcn_s_sleep(2);
    __syncthreads();
    __threadfence();

    // ================= phase 1: apply1 (V = x) =================
    {
        f32x16 acc = {};
        float Lp = 0.f;
        apply_loop(esfB, vtf1 + (size_t)b * 32768, w, l, bhi, blo, acc, Lp);

        Lp += __shfl_xor(Lp, 32);
        #pragma unroll
        for (int r = 0; r < 16; ++r) {
            int d = (r & 3) + 8 * (r >> 2) + 4 * h;
            ps[w * 1056 + d * 33 + q] = acc[r];
        }
        if (l < 32) Ls[w * 32 + l] = Lp;
        __syncthreads();

        const int qq = tid >> 3, dg = tid & 7;
        const float iL = 1.f / (Ls[qq] + Ls[32 + qq] + Ls[64 + qq] + Ls[96 + qq]);
        #pragma unroll
        for (int i = 0; i < 4; ++i) {
            int d = dg * 4 + i;
            yb[qq * 36 + d] = (ps[d * 33 + qq] + ps[1056 + d * 33 + qq] +
                               ps[2112 + d * 33 + qq] + ps[3168 + d * 33 + qq]) * iL;
        }
        __syncthreads();
        if (tid < 128) {   // vtf2 slice from yb
            int fr = tid >> 6, l2 = tid & 63;
            int d = l2 & 31, h2 = l2 >> 5;
            bf16x8 ov;
            #pragma unroll
            for (int j = 0; j < 8; ++j)
                ov[j] = (__bf16)yb[moff(fr, h2, j) * 36 + d];
            *(bf16x8*)(vtf2 + ((size_t)gnt * 2 + fr) * 512 + l2 * 8) = ov;
        }
    }

    // ---- barrier 1: publish vtf2 (W long since done; checked here too) ----
    __threadfence();
    __syncthreads();
    if (tid == 0)
        __hip_atomic_store(&flags[512 + b * 32 + nt], 1u, __ATOMIC_RELEASE, __HIP_MEMORY_SCOPE_AGENT);
    if (tid < 32) {
        while (!__hip_atomic_load(&flags[512 + b * 32 + tid], __ATOMIC_RELAXED, __HIP_MEMORY_SCOPE_AGENT))
            __builtin_amdgcn_s_sleep(2);
    } else if (tid >= 64 && tid < 112) {
        while (!__hip_atomic_load(&flags[1024 + (tid - 64)], __ATOMIC_RELAXED, __HIP_MEMORY_SCOPE_AGENT))
            __builtin_amdgcn_s_sleep(2);
    }
    __syncthreads();
    __threadfence();

    // ================= phase 2: apply2 + fused final =================
    {
        f32x16 acc = {};
        float Lp = 0.f;
        apply_loop(esfB, vtf2 + (size_t)b * 32768, w, l, bhi, blo, acc, Lp);

        Lp += __shfl_xor(Lp, 32);
        #pragma unroll
        for (int r = 0; r < 16; ++r) {
            int d = (r & 3) + 8 * (r >> 2) + 4 * h;
            ps[w * 1056 + d * 33 + q] = acc[r];
        }
        if (l < 32) Ls[w * 32 + l] = Lp;
        __syncthreads();

        const int qq = tid >> 3, dg = tid & 7;
        {   // xg2 = 2*y2 - x
            const float iL = 1.f / (Ls[qq] + Ls[32 + qq] + Ls[64 + qq] + Ls[96 + qq]);
            float4 xv = *(const float4*)(x + (size_t)(b * kN + q0 + qq) * 32 + dg * 4);
            float xa[4] = {xv.x, xv.y, xv.z, xv.w};
            bf16x4 hi, lo;
            #pragma unroll
            for (int i = 0; i < 4; ++i) {
                int d = dg * 4 + i;
                float y2v = (ps[d * 33 + qq] + ps[1056 + d * 33 + qq] +
                             ps[2112 + d * 33 + qq] + ps[3168 + d * 33 + qq]) * iL;
                bfhl tt = hilo(2.f * y2v - xa[i]);
                hi[i] = tt.h; lo[i] = tt.l;
            }
            *(bf16x4*)(xg2 + qq * 36 + dg * 4)        = hi;
            *(bf16x4*)(xg2 + 1152 + qq * 36 + dg * 4) = lo;
        }
        __syncthreads();

        // fused final GEMM: out[n,o] = sum_e s[n,e]*(bias[e,o] + sum_ki XG W)
        f32x16 acc2[4] = {};
        const int e0 = w * 4;
        const int o = q;

        #pragma unroll
        for (int ks = 0; ks < 6; ++ks) {
            bf16x8 Ah, Al;
            if (ks < 2) {          // XG k 0..31 = x, from global
                const float* rp = x + (size_t)(b * kN + q0 + q) * 32 + ks * 16 + 8 * h;
                float4 u0 = *(const float4*)rp;
                float4 u1 = *(const float4*)(rp + 4);
                float u[8] = {u0.x, u0.y, u0.z, u0.w, u1.x, u1.y, u1.z, u1.w};
                #pragma unroll
                for (int j = 0; j < 8; ++j) { bfhl tt = hilo(u[j]); Ah[j] = tt.h; Al[j] = tt.l; }
            } else if (ks < 4) {   // XG k 32..63 = y1, from yb (LDS fp32)
                const float* rp = yb + q * 36 + (ks - 2) * 16 + 8 * h;
                float4 u0 = *(const float4*)rp;
                float4 u1 = *(const float4*)(rp + 4);
                float u[8] = {u0.x, u0.y, u0.z, u0.w, u1.x, u1.y, u1.z, u1.w};
                #pragma unroll
                for (int j = 0; j < 8; ++j) { bfhl tt = hilo(u[j]); Ah[j] = tt.h; Al[j] = tt.l; }
            } else {               // XG k 64..95 = 2*y2-x, from xg2 (bf16)
                const int base = o * 36 + (ks - 4) * 16 + 8 * h;
                bf16x4 a0 = *(const bf16x4*)(xg2 + base);
                bf16x4 a1 = *(const bf16x4*)(xg2 + base + 4);
                bf16x4 b0 = *(const bf16x4*)(xg2 + 1152 + base);
                bf16x4 b1 = *(const bf16x4*)(xg2 + 1152 + base + 4);
                #pragma unroll
                for (int j = 0; j < 4; ++j) {
                    Ah[j] = a0[j]; Ah[4 + j] = a1[j];
                    Al[j] = b0[j]; Al[4 + j] = b1[j];
                }
            }
            #pragma unroll
            for (int ei = 0; ei < 4; ++ei) {
                bf16x8 Bh = *(const bf16x8*)(wq + (size_t)((e0 + ei) * 6 + ks) * 512 + o * 16 + h * 8);
                acc2[ei] = __builtin_amdgcn_mfma_f32_32x32x16_bf16(Ah, Bh, acc2[ei], 0, 0, 0);
                acc2[ei] = __builtin_amdgcn_mfma_f32_32x32x16_bf16(Al, Bh, acc2[ei], 0, 0, 0);
            }
        }

        float pr[16];
        #pragma unroll
        for (int r = 0; r < 16; ++r) pr[r] = 0.f;
        #pragma unroll
        for (int ei = 0; ei < 4; ++ei) {
            const int eg = e0 + ei;
            const float bv = bias[eg * 32 + o];
            #pragma unroll
            for (int r = 0; r < 16; ++r) {
                int node = (r & 3) + 8 * (r >> 2) + 4 * h;
                pr[r] += s_s[node * 16 + eg] * (acc2[ei][r] + bv);
            }
        }
        #pragma unroll
        for (int r = 0; r < 16; ++r) {
            int node = (r & 3) + 8 * (r >> 2) + 4 * h;
            ps[w * 1056 + node * 33 + o] = pr[r];
        }
        __syncthreads();
        {
            const int node = tid >> 3, og = (tid & 7) * 4;
            float4 s;
            #pragma unroll
            for (int i = 0; i < 4; ++i) {
                int c = node * 33 + og + i;
                ((float*)&s)[i] = ps[c] + ps[1056 + c] + ps[2112 + c] + ps[3168 + c];
            }
            *(float4*)(out + (size_t)(b * kN + q0 + node) * 32 + og) = s;
        }
    }
}

extern "C" void kernel_launch(void* const* d_in, const int* in_sizes, int n_in,
                              void* d_out, int out_size, void* d_ws, size_t ws_size,
                              hipStream_t stream) {
    const float* x     = (const float*)d_in[0];
    const float* aemb  = (const float*)d_in[1];
    const float* stock = (const float*)d_in[2];
    const float* Wp    = (const float*)d_in[3];
    const float* bias  = (const float*)d_in[4];
    float* out = (float*)d_out;

    __bf16* wsb  = (__bf16*)d_ws;
    __bf16* esf  = wsb;               // 524288 bf16
    __bf16* vtf1 = wsb + 524288;      // 524288 bf16
    __bf16* vtf2 = wsb + 1048576;     // 524288 bf16
    __bf16* wq   = wsb + 1572864;     // 49152 bf16
    uint32_t* flags = (uint32_t*)(wsb + 1622016);   // 1072 u32 used

    hipMemsetAsync(flags, 0, 8192, stream);
    dygcn_one<<<dim3(512), dim3(256), 0, stream>>>(
        aemb, x, Wp, stock, bias, esf, vtf1, vtf2, wq, flags, out);
}

// Round 12
// 28.999 us; speedup vs baseline: 6.1037x; 6.1037x over previous
//
#include <hip/hip_runtime.h>
#include <stdint.h>

typedef __bf16 bf16x8 __attribute__((ext_vector_type(8)));
typedef __bf16 bf16x4 __attribute__((ext_vector_type(4)));
typedef float  f32x16 __attribute__((ext_vector_type(16)));

constexpr int kB = 16;
constexpr int kN = 1024;
constexpr float kLog2e = 1.44269504088896340736f;

struct bfhl { __bf16 h, l; };
__device__ __forceinline__ bfhl hilo(float v) {
    bfhl r;
    r.h = (__bf16)v;
    r.l = (__bf16)(v - (float)r.h);
    return r;
}

// m-offset ordering of P fragments: P0[j] holds row (j<4 ? j+4h : j+4+4h),
// P1 the same +16. V fragments are consumed in the identical order.
__device__ __forceinline__ int moff(int f, int h, int j) {
    return 16 * f + ((j < 4) ? (4 * h + j) : (4 * h + j + 4));
}

// ---------------------------------------------------------------------------
// Two kernels total (prep eliminated — operands converted inline from fp32):
//  STAGE 1: V = x (on-the-fly frags); epilogue -> vtf2 frags + y1f frags.
//           blocks 0..47 additionally convert Wp -> wq (used by stage 2).
//  STAGE 2: V = vtf2 (bf16 frags from global); epilogue = fused final -> out.
// grid 512 (XCD-swizzled), 256 threads (4 waves; wave w owns kt = w*8+it).
// Fragment conventions (lane = h*32 + (l&31)):
//  QK A/B: E[kt*32+(l&31)][8h+j]  (B-side scaled by log2e, hi/lo exact split)
//  PV A  : V[d=(l&31)][kt*32+moff(f,h,j)]
//  wq    : W_hi[16ks+8h+j][o] at [e][ks][o*16+h*8+j]
// ---------------------------------------------------------------------------
template<int STAGE>
__global__ __launch_bounds__(256, 2) void apply_mfma(
    const float* __restrict__ emb, const float* __restrict__ x,
    const float* __restrict__ Wp,
    const float* __restrict__ stock, const float* __restrict__ bias,
    const __bf16* __restrict__ vtin,   // stage 2: vtf2
    __bf16* __restrict__ vtout,        // stage 1: vtf2
    __bf16* __restrict__ y1f,
    __bf16* __restrict__ wq,
    float* __restrict__ out)
{
    __shared__ alignas(16) char smem[28672];
    float*  ps  = (float*)smem;             // 4224 f32
    float*  Ls  = (float*)(smem + 16896);   // 128 f32
    float*  yb  = (float*)(smem + 17408);   // 32*36 f32 (y1 merge)
    __bf16* xg2 = (__bf16*)(smem + 22016);  // [2][32][36] bf16 (stage2)
    float*  s_s = (float*)(smem + 26624);   // 32*16 f32 (stage2)

    const int tid = threadIdx.x;
    const int w = tid >> 6, l = tid & 63;
    const int q = l & 31, h = l >> 5;
    const int bs = ((blockIdx.x & 7) << 6) | (blockIdx.x >> 3);   // XCD swizzle
    const int b = bs >> 5, nt = bs & 31, q0 = nt << 5;
    const int gnt = b * 32 + nt;

    const float* embB = emb + (size_t)b * kN * 16;
    const float* xB   = x + (size_t)b * kN * 32;
    const __bf16* vtinB = vtin + (size_t)b * 32768;

    if (STAGE == 1) {   // W -> wq (hi plane), done once, consumed by stage 2
        if (blockIdx.x < 48 && tid < 128) {
            int idx = blockIdx.x * 128 + tid;   // (e, ks, o, hh)
            int e = idx / 384, rem = idx - e * 384;
            int ks = rem / 64, r2 = rem - ks * 64;
            int o = r2 >> 1, hh = r2 & 1;
            int ki0 = ks * 16 + hh * 8;
            bf16x8 hi;
            #pragma unroll
            for (int j = 0; j < 8; ++j)
                hi[j] = (__bf16)Wp[(size_t)e * 3072 + (size_t)(ki0 + j) * 32 + o];
            *(bf16x8*)(wq + (size_t)(e * 6 + ks) * 512 + o * 16 + hh * 8) = hi;
        }
    }
    if (STAGE == 2) {   // stage stock tile (read after merge sync)
        int r = tid >> 3, e2 = (tid & 7) * 2;
        *(float2*)(s_s + r * 16 + e2) =
            *(const float2*)(stock + (size_t)(b * kN + q0 + r) * 16 + e2);
    }

    // Q-side B-fragments: own E rows, log2e-scaled exact hi/lo split
    bf16x8 bhi, blo;
    {
        const float* ep = embB + (size_t)(q0 + q) * 16 + 8 * h;
        float4 u0 = *(const float4*)ep;
        float4 u1 = *(const float4*)(ep + 4);
        float u[8] = {u0.x, u0.y, u0.z, u0.w, u1.x, u1.y, u1.z, u1.w};
        #pragma unroll
        for (int j = 0; j < 8; ++j) {
            bfhl t = hilo(u[j] * kLog2e);
            bhi[j] = t.h; blo[j] = t.l;
        }
    }

    f32x16 acc = {};
    float Lp = 0.f;

#define LOADE(kt_, e0_, e1_) {                                            \
    const float* ep_ = embB + (size_t)((kt_) * 32 + q) * 16 + 8 * h;      \
    e0_ = *(const float4*)ep_; e1_ = *(const float4*)(ep_ + 4); }
#define LOADV1(kt_, vv_) {                                                \
    _Pragma("unroll")                                                     \
    for (int j_ = 0; j_ < 8; ++j_) {                                      \
        vv_[j_]     = xB[(size_t)((kt_) * 32 + moff(0, h, j_)) * 32 + q]; \
        vv_[8 + j_] = xB[(size_t)((kt_) * 32 + moff(1, h, j_)) * 32 + q]; } }
#define LOADV2(kt_, A0_, A1_) {                                           \
    A0_ = *(const bf16x8*)(vtinB + ((size_t)(kt_) * 2) * 512 + l * 8);    \
    A1_ = *(const bf16x8*)(vtinB + ((size_t)(kt_) * 2 + 1) * 512 + l * 8); }

    {
        const int ktb = w * 8;
        float4 e0c, e1c, e0n, e1n;
        float vc[16], vn[16];
        bf16x8 A0c, A1c, A0n, A1n;

        LOADE(ktb, e0c, e1c);
        if (STAGE == 1) { LOADV1(ktb, vc) } else { LOADV2(ktb, A0c, A1c) }

        #pragma unroll
        for (int it = 0; it < 8; ++it) {
            if (it < 7) {
                LOADE(ktb + it + 1, e0n, e1n);
                if (STAGE == 1) { LOADV1(ktb + it + 1, vn) }
                else            { LOADV2(ktb + it + 1, A0n, A1n) }
            }
            // convert current E (exact hi/lo) and V (bf16) fragments
            float ef[8] = {e0c.x, e0c.y, e0c.z, e0c.w, e1c.x, e1c.y, e1c.z, e1c.w};
            bf16x8 ahi, alo;
            #pragma unroll
            for (int j = 0; j < 8; ++j) {
                bfhl t = hilo(ef[j]);
                ahi[j] = t.h; alo[j] = t.l;
            }
            bf16x8 A0, A1;
            if (STAGE == 1) {
                #pragma unroll
                for (int j = 0; j < 8; ++j) {
                    A0[j] = (__bf16)vc[j];
                    A1[j] = (__bf16)vc[8 + j];
                }
            } else { A0 = A0c; A1 = A1c; }

            __builtin_amdgcn_s_setprio(1);
            f32x16 S = {};
            S = __builtin_amdgcn_mfma_f32_32x32x16_bf16(ahi, bhi, S, 0, 0, 0);
            S = __builtin_amdgcn_mfma_f32_32x32x16_bf16(ahi, blo, S, 0, 0, 0);
            S = __builtin_amdgcn_mfma_f32_32x32x16_bf16(alo, bhi, S, 0, 0, 0);
            __builtin_amdgcn_s_setprio(0);

            float p[16];
            #pragma unroll
            for (int r = 0; r < 16; ++r) {
                p[r] = exp2f(fmaxf(S[r], 0.f));
                Lp += p[r];
            }
            bf16x8 P0, P1;
            #pragma unroll
            for (int j = 0; j < 8; ++j) { P0[j] = (__bf16)p[j]; P1[j] = (__bf16)p[8 + j]; }

            __builtin_amdgcn_s_setprio(1);
            acc = __builtin_amdgcn_mfma_f32_32x32x16_bf16(A0, P0, acc, 0, 0, 0);
            acc = __builtin_amdgcn_mfma_f32_32x32x16_bf16(A1, P1, acc, 0, 0, 0);
            __builtin_amdgcn_s_setprio(0);

            e0c = e0n; e1c = e1n;
            if (STAGE == 1) {
                #pragma unroll
                for (int j = 0; j < 16; ++j) vc[j] = vn[j];
            } else { A0c = A0n; A1c = A1n; }
        }
    }
#undef LOADE
#undef LOADV1
#undef LOADV2

    // ---- merge 4 wave-partials ----
    Lp += __shfl_xor(Lp, 32);
    #pragma unroll
    for (int r = 0; r < 16; ++r) {
        int d = (r & 3) + 8 * (r >> 2) + 4 * h;
        ps[w * 1056 + d * 33 + q] = acc[r];
    }
    if (l < 32) Ls[w * 32 + l] = Lp;
    __syncthreads();

    const int qq = tid >> 3, dg = tid & 7;
    const float iL = 1.f / (Ls[qq] + Ls[32 + qq] + Ls[64 + qq] + Ls[96 + qq]);
    float yv[4];
    #pragma unroll
    for (int i = 0; i < 4; ++i) {
        int d = dg * 4 + i;
        yv[i] = (ps[d * 33 + qq] + ps[1056 + d * 33 + qq] +
                 ps[2112 + d * 33 + qq] + ps[3168 + d * 33 + qq]) * iL;
    }

    if (STAGE == 1) {
        #pragma unroll
        for (int i = 0; i < 4; ++i) yb[qq * 36 + dg * 4 + i] = yv[i];
        __syncthreads();
        if (tid < 128) {   // vtf2 fragments
            int fr = tid >> 6, l2 = tid & 63;
            int d = l2 & 31, h2 = l2 >> 5;
            bf16x8 ov;
            #pragma unroll
            for (int j = 0; j < 8; ++j)
                ov[j] = (__bf16)yb[moff(fr, h2, j) * 36 + d];
            *(bf16x8*)(vtout + ((size_t)gnt * 2 + fr) * 512 + l2 * 8) = ov;
        }
        {   // y1f fragments (hi/lo planes)
            int ks2 = tid >> 7, pl = (tid >> 6) & 1, l2 = tid & 63;
            int node = l2 & 31, h2 = l2 >> 5;
            const float* rp = yb + node * 36 + ks2 * 16 + 8 * h2;
            bf16x8 ov;
            #pragma unroll
            for (int j = 0; j < 8; ++j) {
                bfhl tt = hilo(rp[j]);
                ov[j] = pl ? tt.l : tt.h;
            }
            *(bf16x8*)(y1f + (((size_t)gnt * 2 + ks2) * 2 + pl) * 512 + l2 * 8) = ov;
        }
    } else {
        // ---- fused final: xg2 = 2*y2 - x (k 64..95), then out ----
        {
            float4 xv = *(const float4*)(xB + (size_t)(q0 + qq) * 32 + dg * 4);
            float xa[4] = {xv.x, xv.y, xv.z, xv.w};
            bf16x4 hi, lo;
            #pragma unroll
            for (int i = 0; i < 4; ++i) {
                bfhl tt = hilo(2.f * yv[i] - xa[i]);
                hi[i] = tt.h; lo[i] = tt.l;
            }
            *(bf16x4*)(xg2 + qq * 36 + dg * 4)        = hi;
            *(bf16x4*)(xg2 + 1152 + qq * 36 + dg * 4) = lo;
        }
        __syncthreads();

        f32x16 acc2[4] = {};
        const int e0 = w * 4;
        const int o = q;   // A-side node index == B/D-side o index

        #pragma unroll
        for (int ks = 0; ks < 6; ++ks) {
            bf16x8 Ah, Al;
            if (ks < 2) {          // XG k 0..31 = x, from global
                const float* rp = xB + (size_t)(q0 + q) * 32 + ks * 16 + 8 * h;
                float4 u0 = *(const float4*)rp;
                float4 u1 = *(const float4*)(rp + 4);
                float u[8] = {u0.x, u0.y, u0.z, u0.w, u1.x, u1.y, u1.z, u1.w};
                #pragma unroll
                for (int j = 0; j < 8; ++j) { bfhl tt = hilo(u[j]); Ah[j] = tt.h; Al[j] = tt.l; }
            } else if (ks < 4) {   // XG k 32..63 = y1, from y1f frags
                Ah = *(const bf16x8*)(y1f + (((size_t)gnt * 2 + (ks - 2)) * 2 + 0) * 512 + l * 8);
                Al = *(const bf16x8*)(y1f + (((size_t)gnt * 2 + (ks - 2)) * 2 + 1) * 512 + l * 8);
            } else {               // XG k 64..95 = 2*y2-x, from xg2 LDS
                const int base = o * 36 + (ks - 4) * 16 + 8 * h;
                bf16x4 a0 = *(const bf16x4*)(xg2 + base);
                bf16x4 a1 = *(const bf16x4*)(xg2 + base + 4);
                bf16x4 b0 = *(const bf16x4*)(xg2 + 1152 + base);
                bf16x4 b1 = *(const bf16x4*)(xg2 + 1152 + base + 4);
                #pragma unroll
                for (int j = 0; j < 4; ++j) {
                    Ah[j] = a0[j]; Ah[4 + j] = a1[j];
                    Al[j] = b0[j]; Al[4 + j] = b1[j];
                }
            }
            #pragma unroll
            for (int ei = 0; ei < 4; ++ei) {
                bf16x8 Bh = *(const bf16x8*)(wq + (size_t)((e0 + ei) * 6 + ks) * 512 + o * 16 + h * 8);
                acc2[ei] = __builtin_amdgcn_mfma_f32_32x32x16_bf16(Ah, Bh, acc2[ei], 0, 0, 0);
                acc2[ei] = __builtin_amdgcn_mfma_f32_32x32x16_bf16(Al, Bh, acc2[ei], 0, 0, 0);
            }
        }

        float pr[16];
        #pragma unroll
        for (int r = 0; r < 16; ++r) pr[r] = 0.f;
        #pragma unroll
        for (int ei = 0; ei < 4; ++ei) {
            const int eg = e0 + ei;
            const float bv = bias[eg * 32 + o];
            #pragma unroll
            for (int r = 0; r < 16; ++r) {
                int node = (r & 3) + 8 * (r >> 2) + 4 * h;
                pr[r] += s_s[node * 16 + eg] * (acc2[ei][r] + bv);
            }
        }
        #pragma unroll
        for (int r = 0; r < 16; ++r) {
            int node = (r & 3) + 8 * (r >> 2) + 4 * h;
            ps[w * 1056 + node * 33 + o] = pr[r];
        }
        __syncthreads();
        {
            const int node = tid >> 3, og = (tid & 7) * 4;
            float4 s;
            #pragma unroll
            for (int i = 0; i < 4; ++i) {
                int c = node * 33 + og + i;
                ((float*)&s)[i] = ps[c] + ps[1056 + c] + ps[2112 + c] + ps[3168 + c];
            }
            *(float4*)(out + (size_t)(b * kN + q0 + node) * 32 + og) = s;
        }
    }
}

extern "C" void kernel_launch(void* const* d_in, const int* in_sizes, int n_in,
                              void* d_out, int out_size, void* d_ws, size_t ws_size,
                              hipStream_t stream) {
    const float* x     = (const float*)d_in[0];
    const float* aemb  = (const float*)d_in[1];
    const float* stock = (const float*)d_in[2];
    const float* Wp    = (const float*)d_in[3];
    const float* bias  = (const float*)d_in[4];
    float* out = (float*)d_out;

    __bf16* wsb  = (__bf16*)d_ws;
    __bf16* vtf2 = wsb;               // 524288 bf16
    __bf16* y1f  = wsb + 524288;      // 1048576 bf16
    __bf16* wq   = wsb + 1572864;     // 49152 bf16

    apply_mfma<1><<<dim3(512), dim3(256), 0, stream>>>(
        aemb, x, Wp, stock, bias, nullptr, vtf2, y1f, wq, out);
    apply_mfma<2><<<dim3(512), dim3(256), 0, stream>>>(
        aemb, x, Wp, stock, bias, vtf2, nullptr, y1f, wq, out);
}

// Round 13
// 28.858 us; speedup vs baseline: 6.1334x; 1.0049x over previous
//
#include <hip/hip_runtime.h>
#include <stdint.h>

typedef __bf16 bf16x8 __attribute__((ext_vector_type(8)));
typedef __bf16 bf16x4 __attribute__((ext_vector_type(4)));
typedef __bf16 bf16x2 __attribute__((ext_vector_type(2)));
typedef float  f32x16 __attribute__((ext_vector_type(16)));

constexpr int kB = 16;
constexpr int kN = 1024;
constexpr float kLog2e = 1.44269504088896340736f;

struct bfhl { __bf16 h, l; };
__device__ __forceinline__ bfhl hilo(float v) {
    bfhl r;
    r.h = (__bf16)v;
    r.l = (__bf16)(v - (float)r.h);
    return r;
}

// m-offset ordering of P fragments: P0[j] holds row (j<4 ? j+4h : j+4+4h),
// P1 the same +16. V fragments are consumed in the identical order.
__device__ __forceinline__ int moff(int f, int h, int j) {
    return 16 * f + ((j < 4) ? (4 * h + j) : (4 * h + j + 4));
}

// ---------------------------------------------------------------------------
// Two kernels; 512-thread blocks (8 waves) for 16 waves/CU occupancy.
//  STAGE 1: V = x (on-the-fly frags); epilogue -> vtf2 frags + y1f frags.
//           blocks 0..47 additionally convert Wp -> wq (used by stage 2).
//  STAGE 2: V = vtf2 (bf16 frags); epilogue = fused final GEMM -> out.
// grid 512 (XCD-swizzled). Wave w owns k-tiles kt = w*4 + it (it<4).
// Fragment conventions (lane = h*32 + (l&31)):
//  QK A/B: E[kt*32+(l&31)][8h+j]  (B-side scaled by log2e, hi/lo exact split)
//  PV A  : V[d=(l&31)][kt*32+moff(f,h,j)]
//  wq    : W_hi[16ks+8h+j][o] at [e][ks][o*16+h*8+j]
// ---------------------------------------------------------------------------
template<int STAGE>
__global__ __launch_bounds__(512, 4) void apply_mfma(
    const float* __restrict__ emb, const float* __restrict__ x,
    const float* __restrict__ Wp,
    const float* __restrict__ stock, const float* __restrict__ bias,
    const __bf16* __restrict__ vtin,   // stage 2: vtf2
    __bf16* __restrict__ vtout,        // stage 1: vtf2
    __bf16* __restrict__ y1f,
    __bf16* __restrict__ wq,
    float* __restrict__ out)
{
    __shared__ alignas(16) char smem[41472];
    float*  ps  = (float*)smem;             // 8448 f32 (8 waves x 1056)
    float*  Ls  = (float*)(smem + 33792);   // 256 f32
    float*  yb  = (float*)(smem + 34816);   // stage1: 32*36 f32
    __bf16* xg2 = (__bf16*)(smem + 34816);  // stage2: [2][32][36] bf16
    float*  s_s = (float*)(smem + 39424);   // stage2: 32*16 f32

    const int tid = threadIdx.x;
    const int w = tid >> 6, l = tid & 63;
    const int q = l & 31, h = l >> 5;
    const int bs = ((blockIdx.x & 7) << 6) | (blockIdx.x >> 3);   // XCD swizzle
    const int b = bs >> 5, nt = bs & 31, q0 = nt << 5;
    const int gnt = b * 32 + nt;

    const float* embB = emb + (size_t)b * kN * 16;
    const float* xB   = x + (size_t)b * kN * 32;
    const __bf16* vtinB = vtin + (size_t)b * 32768;

    if (STAGE == 1) {   // W -> wq (hi plane), consumed by stage 2
        if (blockIdx.x < 48 && tid < 128) {
            int idx = blockIdx.x * 128 + tid;   // (e, ks, o, hh)
            int e = idx / 384, rem = idx - e * 384;
            int ks = rem / 64, r2 = rem - ks * 64;
            int o = r2 >> 1, hh = r2 & 1;
            int ki0 = ks * 16 + hh * 8;
            bf16x8 hi;
            #pragma unroll
            for (int j = 0; j < 8; ++j)
                hi[j] = (__bf16)Wp[(size_t)e * 3072 + (size_t)(ki0 + j) * 32 + o];
            *(bf16x8*)(wq + (size_t)(e * 6 + ks) * 512 + o * 16 + hh * 8) = hi;
        }
    }
    if (STAGE == 2) {   // stage stock tile (read after merge sync)
        if (tid < 256) {
            int r = tid >> 3, e2 = (tid & 7) * 2;
            *(float2*)(s_s + r * 16 + e2) =
                *(const float2*)(stock + (size_t)(b * kN + q0 + r) * 16 + e2);
        }
    }

    // Q-side B-fragments: own E rows, log2e-scaled exact hi/lo split
    bf16x8 bhi, blo;
    {
        const float* ep = embB + (size_t)(q0 + q) * 16 + 8 * h;
        float4 u0 = *(const float4*)ep;
        float4 u1 = *(const float4*)(ep + 4);
        float u[8] = {u0.x, u0.y, u0.z, u0.w, u1.x, u1.y, u1.z, u1.w};
        #pragma unroll
        for (int j = 0; j < 8; ++j) {
            bfhl t = hilo(u[j] * kLog2e);
            bhi[j] = t.h; blo[j] = t.l;
        }
    }

    f32x16 acc = {};
    float Lp = 0.f;

    {
        const int ktb = w * 4;
        #pragma unroll
        for (int it = 0; it < 4; ++it) {
            const int kt = ktb + it;
            // E fragment: load + exact hi/lo convert
            bf16x8 ahi, alo;
            {
                const float* ep = embB + (size_t)(kt * 32 + q) * 16 + 8 * h;
                float4 u0 = *(const float4*)ep;
                float4 u1 = *(const float4*)(ep + 4);
                float u[8] = {u0.x, u0.y, u0.z, u0.w, u1.x, u1.y, u1.z, u1.w};
                #pragma unroll
                for (int j = 0; j < 8; ++j) {
                    bfhl t = hilo(u[j]);
                    ahi[j] = t.h; alo[j] = t.l;
                }
            }
            // V fragments
            bf16x8 A0, A1;
            if (STAGE == 1) {
                #pragma unroll
                for (int j = 0; j < 8; ++j) {
                    A0[j] = (__bf16)xB[(size_t)(kt * 32 + moff(0, h, j)) * 32 + q];
                    A1[j] = (__bf16)xB[(size_t)(kt * 32 + moff(1, h, j)) * 32 + q];
                }
            } else {
                A0 = *(const bf16x8*)(vtinB + ((size_t)kt * 2) * 512 + l * 8);
                A1 = *(const bf16x8*)(vtinB + ((size_t)kt * 2 + 1) * 512 + l * 8);
            }

            __builtin_amdgcn_s_setprio(1);
            f32x16 S = {};
            S = __builtin_amdgcn_mfma_f32_32x32x16_bf16(ahi, bhi, S, 0, 0, 0);
            S = __builtin_amdgcn_mfma_f32_32x32x16_bf16(ahi, blo, S, 0, 0, 0);
            S = __builtin_amdgcn_mfma_f32_32x32x16_bf16(alo, bhi, S, 0, 0, 0);
            __builtin_amdgcn_s_setprio(0);

            float p[16];
            #pragma unroll
            for (int r = 0; r < 16; ++r) {
                p[r] = exp2f(fmaxf(S[r], 0.f));
                Lp += p[r];
            }
            bf16x8 P0, P1;
            #pragma unroll
            for (int j = 0; j < 8; ++j) { P0[j] = (__bf16)p[j]; P1[j] = (__bf16)p[8 + j]; }

            __builtin_amdgcn_s_setprio(1);
            acc = __builtin_amdgcn_mfma_f32_32x32x16_bf16(A0, P0, acc, 0, 0, 0);
            acc = __builtin_amdgcn_mfma_f32_32x32x16_bf16(A1, P1, acc, 0, 0, 0);
            __builtin_amdgcn_s_setprio(0);
        }
    }

    // ---- merge 8 wave-partials ----
    Lp += __shfl_xor(Lp, 32);
    #pragma unroll
    for (int r = 0; r < 16; ++r) {
        int d = (r & 3) + 8 * (r >> 2) + 4 * h;
        ps[w * 1056 + d * 33 + q] = acc[r];
    }
    if (l < 32) Ls[w * 32 + l] = Lp;
    __syncthreads();

    const int qq = tid >> 4, dgi = tid & 15;
    float yv[2];
    {
        float Lsum = 0.f;
        #pragma unroll
        for (int k = 0; k < 8; ++k) Lsum += Ls[k * 32 + qq];
        const float iL = 1.f / Lsum;
        #pragma unroll
        for (int i = 0; i < 2; ++i) {
            int d = dgi * 2 + i;
            float s = 0.f;
            #pragma unroll
            for (int k = 0; k < 8; ++k) s += ps[k * 1056 + d * 33 + qq];
            yv[i] = s * iL;
        }
    }

    if (STAGE == 1) {
        *(float2*)(yb + qq * 36 + dgi * 2) = make_float2(yv[0], yv[1]);
        __syncthreads();
        if (tid < 128) {   // vtf2 fragments
            int fr = tid >> 6, l2 = tid & 63;
            int d = l2 & 31, h2 = l2 >> 5;
            bf16x8 ov;
            #pragma unroll
            for (int j = 0; j < 8; ++j)
                ov[j] = (__bf16)yb[moff(fr, h2, j) * 36 + d];
            *(bf16x8*)(vtout + ((size_t)gnt * 2 + fr) * 512 + l2 * 8) = ov;
        }
        if (tid < 256) {   // y1f fragments (hi/lo planes)
            int ks2 = tid >> 7, pl = (tid >> 6) & 1, l2 = tid & 63;
            int node = l2 & 31, h2 = l2 >> 5;
            const float* rp = yb + node * 36 + ks2 * 16 + 8 * h2;
            bf16x8 ov;
            #pragma unroll
            for (int j = 0; j < 8; ++j) {
                bfhl tt = hilo(rp[j]);
                ov[j] = pl ? tt.l : tt.h;
            }
            *(bf16x8*)(y1f + (((size_t)gnt * 2 + ks2) * 2 + pl) * 512 + l2 * 8) = ov;
        }
    } else {
        // ---- fused final: xg2 = 2*y2 - x (k 64..95), then out ----
        {
            float2 xv = *(const float2*)(xB + (size_t)(q0 + qq) * 32 + dgi * 2);
            bfhl t0 = hilo(2.f * yv[0] - xv.x);
            bfhl t1 = hilo(2.f * yv[1] - xv.y);
            bf16x2 hi2, lo2;
            hi2[0] = t0.h; hi2[1] = t1.h;
            lo2[0] = t0.l; lo2[1] = t1.l;
            *(bf16x2*)(xg2 + qq * 36 + dgi * 2)        = hi2;
            *(bf16x2*)(xg2 + 1152 + qq * 36 + dgi * 2) = lo2;
        }
        __syncthreads();

        f32x16 acc2[2] = {};
        const int e0 = w * 2;
        const int o = q;   // A-side node index == B/D-side o index

        #pragma unroll
        for (int ks = 0; ks < 6; ++ks) {
            bf16x8 Ah, Al;
            if (ks < 2) {          // XG k 0..31 = x, from global
                const float* rp = xB + (size_t)(q0 + q) * 32 + ks * 16 + 8 * h;
                float4 u0 = *(const float4*)rp;
                float4 u1 = *(const float4*)(rp + 4);
                float u[8] = {u0.x, u0.y, u0.z, u0.w, u1.x, u1.y, u1.z, u1.w};
                #pragma unroll
                for (int j = 0; j < 8; ++j) { bfhl tt = hilo(u[j]); Ah[j] = tt.h; Al[j] = tt.l; }
            } else if (ks < 4) {   // XG k 32..63 = y1, from y1f frags
                Ah = *(const bf16x8*)(y1f + (((size_t)gnt * 2 + (ks - 2)) * 2 + 0) * 512 + l * 8);
                Al = *(const bf16x8*)(y1f + (((size_t)gnt * 2 + (ks - 2)) * 2 + 1) * 512 + l * 8);
            } else {               // XG k 64..95 = 2*y2-x, from xg2 LDS
                const int base = o * 36 + (ks - 4) * 16 + 8 * h;
                bf16x4 a0 = *(const bf16x4*)(xg2 + base);
                bf16x4 a1 = *(const bf16x4*)(xg2 + base + 4);
                bf16x4 b0 = *(const bf16x4*)(xg2 + 1152 + base);
                bf16x4 b1 = *(const bf16x4*)(xg2 + 1152 + base + 4);
                #pragma unroll
                for (int j = 0; j < 4; ++j) {
                    Ah[j] = a0[j]; Ah[4 + j] = a1[j];
                    Al[j] = b0[j]; Al[4 + j] = b1[j];
                }
            }
            #pragma unroll
            for (int ei = 0; ei < 2; ++ei) {
                bf16x8 Bh = *(const bf16x8*)(wq + (size_t)((e0 + ei) * 6 + ks) * 512 + o * 16 + h * 8);
                acc2[ei] = __builtin_amdgcn_mfma_f32_32x32x16_bf16(Ah, Bh, acc2[ei], 0, 0, 0);
                acc2[ei] = __builtin_amdgcn_mfma_f32_32x32x16_bf16(Al, Bh, acc2[ei], 0, 0, 0);
            }
        }

        float pr[16];
        #pragma unroll
        for (int r = 0; r < 16; ++r) pr[r] = 0.f;
        #pragma unroll
        for (int ei = 0; ei < 2; ++ei) {
            const int eg = e0 + ei;
            const float bv = bias[eg * 32 + o];
            #pragma unroll
            for (int r = 0; r < 16; ++r) {
                int node = (r & 3) + 8 * (r >> 2) + 4 * h;
                pr[r] += s_s[node * 16 + eg] * (acc2[ei][r] + bv);
            }
        }
        #pragma unroll
        for (int r = 0; r < 16; ++r) {
            int node = (r & 3) + 8 * (r >> 2) + 4 * h;
            ps[w * 1056 + node * 33 + o] = pr[r];
        }
        __syncthreads();
        {
            const int node = tid >> 4, og = (tid & 15) * 2;
            float2 s = make_float2(0.f, 0.f);
            #pragma unroll
            for (int k = 0; k < 8; ++k) {
                int c = k * 1056 + node * 33 + og;
                s.x += ps[c];
                s.y += ps[c + 1];
            }
            *(float2*)(out + (size_t)(b * kN + q0 + node) * 32 + og) = s;
        }
    }
}

extern "C" void kernel_launch(void* const* d_in, const int* in_sizes, int n_in,
                              void* d_out, int out_size, void* d_ws, size_t ws_size,
                              hipStream_t stream) {
    const float* x     = (const float*)d_in[0];
    const float* aemb  = (const float*)d_in[1];
    const float* stock = (const float*)d_in[2];
    const float* Wp    = (const float*)d_in[3];
    const float* bias  = (const float*)d_in[4];
    float* out = (float*)d_out;

    __bf16* wsb  = (__bf16*)d_ws;
    __bf16* vtf2 = wsb;               // 524288 bf16
    __bf16* y1f  = wsb + 524288;      // 1048576 bf16
    __bf16* wq   = wsb + 1572864;     // 49152 bf16

    apply_mfma<1><<<dim3(512), dim3(512), 0, stream>>>(
        aemb, x, Wp, stock, bias, nullptr, vtf2, y1f, wq, out);
    apply_mfma<2><<<dim3(512), dim3(512), 0, stream>>>(
        aemb, x, Wp, stock, bias, vtf2, nullptr, y1f, wq, out);
}